// Round 12
// baseline (2051.572 us; speedup 1.0000x reference)
//
#include <hip/hip_runtime.h>
#include <math.h>

// ---------------------------------------------------------------------------
// CurvePredictor R19: R18 + h0 register-prefetch under the shadow.
// R18 post-mortem: 2045us warm (7.9us/iter); split-barrier confirmed (+7%).
// Remaining serial budget: h0 stage IC latency + cnt0 detect at iter top.
// R19: the wait for cnt0(s) moves INTO iter s's shadow (peers arrived at
// their mid-critical -> poll already satisfied); h0(s+1) loads issue there
// and land in regs (t0, carried across iters) while G1-exchange/pointwise1/
// publish/decoder-tail run. At iter s+1 top only LDS-write + wbar remain.
// WAR audit: prefetched parity's next writer is peers' iter-s+2 publish,
// gated by their wait cnt0(s+1); we arrive cnt0(s+1) only after arrive-
// cnt1(s)'s vmcnt(0) drain, which completes our prefetch loads -> ordered.
// Everything else identical to R18 (proven): 32 groups x 8 members,
// register-resident Whh0/Wih1/Whh1/W3, relaxed agent atomics, split
// cnt0/cnt1 barriers, A-packed u64 publication, rcp transcendentals,
// 136.5KB LDS -> 1 block/CU, grid 256.
// ---------------------------------------------------------------------------

typedef short s8v __attribute__((ext_vector_type(8)));   // 8 x bf16
typedef float f4v __attribute__((ext_vector_type(4)));   // 4 x f32
typedef unsigned long long u64;

// ws layout (units: shorts)
#define IMG_SH   1084416                 // swizzled weight image
#define H0G_SH   (IMG_SH)                // h0g[2 par][32 g][32 tiles][512]
#define H1G_SH   (H0G_SH + 1048576)
#define CNT_SH   (H1G_SH + 1048576)      // u32 cnt[2][32][260] = 33280 shorts
#define ENC_SH   (CNT_SH + 33280)        // encg[32 g][32 tiles][512]

__device__ __forceinline__ f4v mfma16(s8v a, s8v b, f4v c){
  return __builtin_amdgcn_mfma_f32_16x16x32_bf16(a, b, c, 0, 0, 0);
}
__device__ __forceinline__ short f2bf(float f){
  unsigned u = __float_as_uint(f);
  u = u + 0x7FFFu + ((u >> 16) & 1u);
  return (short)(u >> 16);
}
__device__ __forceinline__ float wred(float v){
  #pragma unroll
  for (int o = 32; o; o >>= 1) v += __shfl_xor(v, o);
  return v;
}
__device__ __forceinline__ float rcpf(float x){ return __builtin_amdgcn_rcpf(x); }
__device__ __forceinline__ float sigm(float x){ return rcpf(1.0f + __expf(-x)); }
__device__ __forceinline__ float tnh(float x){
  x = fminf(15.0f, fmaxf(-15.0f, x));
  float e = __expf(2.0f * x);
  return (e - 1.0f) * rcpf(e + 1.0f);
}
__device__ __forceinline__ float gelu(float v){
  return 0.5f * v * (1.0f + erff(v * 0.70710678118654752440f));
}

// ---- coherent (agent/IC-level) access, compiler-modeled ----
__device__ __forceinline__ u64 ldc8(const u64* p){
  return __hip_atomic_load(p, __ATOMIC_RELAXED, __HIP_MEMORY_SCOPE_AGENT);
}
__device__ __forceinline__ void stc2(short* p, short v){
  __hip_atomic_store(p, v, __ATOMIC_RELAXED, __HIP_MEMORY_SCOPE_AGENT);
}
__device__ __forceinline__ void stc8(u64* p, u64 v){
  __hip_atomic_store(p, v, __ATOMIC_RELAXED, __HIP_MEMORY_SCOPE_AGENT);
}
__device__ __forceinline__ void wbar(){                 // lgkm-only raw barrier
  asm volatile("s_waitcnt lgkmcnt(0)" ::: "memory");
  __builtin_amdgcn_s_barrier();
}
// arrive: all waves' global stores drained, then one agent-relaxed add
__device__ __forceinline__ void arrive_bar(unsigned* c, int tid){
  asm volatile("s_waitcnt vmcnt(0) lgkmcnt(0)" ::: "memory");
  __builtin_amdgcn_s_barrier();
  if (tid == 0)
    __hip_atomic_fetch_add(c, 1u, __ATOMIC_RELAXED, __HIP_MEMORY_SCOPE_AGENT);
}
// wait: poll to 8 members, then release the block
__device__ __forceinline__ void wait_bar(unsigned* c, int tid){
  if (tid == 0){
    unsigned it = 0;
    while (__hip_atomic_load(c, __ATOMIC_RELAXED, __HIP_MEMORY_SCOPE_AGENT) < 8u
           && ++it < (1u << 18))
      __builtin_amdgcn_s_sleep(1);        // failsafe: finite on bug
  }
  __builtin_amdgcn_s_barrier();
  asm volatile("" ::: "memory");          // no hoisting of post-barrier loads
}

// weight image: identical swizzle to R5-R18 (interior lane-linear lane*8):
// mats (1024x256): s*16384 + g*4096 + kk*512 + lane*8 + j ; lane=q*16+m16,
// col=s*16+m16, k=kk*32+q*8+j, gate-row=g*256+col.
// [0,262144) Wih0 [262144,524288) Whh0 [524288,786432) Wih1 [786432,1048576) Whh1
// W3 [128][256]: 1048576 + s2*4096 + kk*512 + lane*8
__global__ void prep_kernel(
    const float* __restrict__ Wih0, const float* __restrict__ Whh0,
    const float* __restrict__ Wih1, const float* __restrict__ Whh1,
    const float* __restrict__ W3,   const float* __restrict__ W4,
    short* __restrict__ wsb)
{
  const int i = blockIdx.x * 256 + threadIdx.x;
  if (i >= 1083392) return;
  float v;
  if (i < 1048576){
    const int seg = i >> 18;
    const int r   = i & 262143;
    const int s   = r >> 14;
    const int g   = (r >> 12) & 3;
    const int kk  = (r >> 9) & 7;
    const int q   = (r >> 7) & 3;
    const int m16 = (r >> 3) & 15;
    const int j   = r & 7;
    const int hid = s * 16 + m16;
    const int k   = kk * 32 + q * 8 + j;
    const float* mt = (seg == 0) ? Wih0 : (seg == 1) ? Whh0 : (seg == 2) ? Wih1 : Whh1;
    v = mt[(g * 256 + hid) * 256 + k];
  } else if (i < 1081344){
    const int r   = i - 1048576;
    const int s2  = r >> 12;
    const int kk  = (r >> 9) & 7;
    const int q   = (r >> 7) & 3;
    const int m16 = (r >> 3) & 15;
    const int j   = r & 7;
    v = W3[(s2 * 16 + m16) * 256 + kk * 32 + q * 8 + j];
  } else {
    const int r   = i - 1081344;
    const int kk  = (r >> 9) & 3;
    const int q   = (r >> 7) & 3;
    const int m16 = (r >> 3) & 15;
    const int j   = r & 7;
    const int k   = kk * 32 + q * 8 + j;
    v = (m16 < 2) ? W4[m16 * 128 + k] : 0.0f;
  }
  wsb[i] = f2bf(v);
}

// h/enc buffers are A-packed (64 rows x 256 cols -> 32 tiles x 512 shorts):
//   tile = (row>>4)*8 + (col>>5); interior = (((col>>3)&3)*16 + (row&15))*8 + (col&7)
// gemm lane (q,m16) reads tile (rt*8+kk) at interior lane*8 (contiguous).
// Pointwise thread tid owns exactly u64 index (tid&127) of tile (tid>>7)*8+m,
// so publication is one stc8 per thread per layer (proven R15-R18).

__global__ __launch_bounds__(512) void curve_rec(
    const float* __restrict__ x,
    const float* __restrict__ W1, const float* __restrict__ b1,
    const float* __restrict__ g1, const float* __restrict__ be1,
    const float* __restrict__ W2, const float* __restrict__ b2,
    const float* __restrict__ g2, const float* __restrict__ be2,
    const float* __restrict__ bih0, const float* __restrict__ bhh0,
    const float* __restrict__ bih1, const float* __restrict__ bhh1,
    const float* __restrict__ b3, const float* __restrict__ b4,
    const float* __restrict__ W4,
    short* __restrict__ wsb,
    float* __restrict__ out)
{
  const int tid  = threadIdx.x;
  const int v    = tid >> 6;          // wave 0..7
  const int lane = tid & 63;
  const int q    = lane >> 4;
  const int m16  = lane & 15;
  const int bid  = blockIdx.x;
  const int g    = bid & 31;          // group (64 batch rows)
  const int m    = bid >> 5;          // member (32 hidden cols)
  const int gate = v & 3;
  const int ch   = v >> 2;            // col-half of the member's 32-col slice

  const short* img = wsb;
  short* h0g  = wsb + H0G_SH;
  short* h1g  = wsb + H1G_SH;
  short* encg = wsb + ENC_SH;
  unsigned* cntb = (unsigned*)(wsb + CNT_SH);
  unsigned* cnt0 = cntb + g * 260;
  unsigned* cnt1 = cntb + 32 * 260 + g * 260;

  __shared__ __align__(16) short ldsH0[16384];     // 32KB: h0 stage
  __shared__ __align__(16) short ldsX [16384];     // 32KB: h1 stage
  __shared__ __align__(16) float Gst[2][256 * 36]; // 72KB: gate exchange
  __shared__ __align__(16) float pstg[128];        // 136.5KB -> 1 blk/CU

  // ---- persistent register-resident weight fragments (loaded once) ----
  s8v Bh0[8], Bi1[8], Bh1[8], W3r[8];
  const int sIdx = 2 * m + ch;        // 16-col image slice index
  #pragma unroll
  for (int kk = 0; kk < 8; kk++){
    const int off = sIdx * 16384 + gate * 4096 + kk * 512 + (lane << 3);
    Bh0[kk] = *(const s8v*)(img + 262144 + off);
    Bi1[kk] = *(const s8v*)(img + 524288 + off);
    Bh1[kk] = *(const s8v*)(img + 786432 + off);
    W3r[kk] = *(const s8v*)(img + 1048576 + v * 4096 + kk * 512 + (lane << 3));
  }
  const float b3c = b3[v * 16 + m16];
  const float w40 = W4[v * 16 + m16];
  const float w41 = W4[128 + v * 16 + m16];
  const float b4o = b4[tid & 1];
  const int   n0  = gate * 256 + m * 32 + ch * 16 + m16;
  const float bs1v = bih1[n0] + bhh1[n0];
  // decoder A constants (rows m*8 + m16-window; rows>=8 feed discarded lanes)
  const int row3 = m * 8 + m16, rt3 = row3 >> 4, rin3 = row3 & 15;
  // pointwise ownership: thread tid -> 4 cells = one u64 of the A-packed slice
  const int rt_p = tid >> 7, rem = tid & 127;
  const int cq_p = (rem >> 5) & 3, r16p = (rem >> 1) & 15, c4h = rem & 1;
  const int rowp  = rt_p * 16 + r16p;            // row within group (0..63)
  const int coltp = cq_p * 8 + c4h * 4;          // col within member slice
  const int pub_off = (rt_p * 8 + m) * 512 + rem * 4;   // shorts in layer chunk

  // ---- encoder: wave v computes batch row m*8+v of this group ----
  {
    const int row_l = m * 8 + v;
    const int r = g * 64 + row_l;
    float xv[5];
    #pragma unroll
    for (int k = 0; k < 5; k++) xv[k] = x[r * 5 + k];
    float a0 = b1[lane], a1 = b1[lane + 64];
    #pragma unroll
    for (int k = 0; k < 5; k++){
      a0 += xv[k] * W1[lane * 5 + k];
      a1 += xv[k] * W1[(lane + 64) * 5 + k];
    }
    a0 = gelu(a0); a1 = gelu(a1);
    float mean = wred(a0 + a1) * (1.0f / 128.0f);
    float d0 = a0 - mean, d1 = a1 - mean;
    float inv = rsqrtf(wred(d0 * d0 + d1 * d1) * (1.0f / 128.0f) + 1e-5f);
    float y0 = d0 * inv * g1[lane]      + be1[lane];
    float y1 = d1 * inv * g1[lane + 64] + be1[lane + 64];

    float acc2[4];
    #pragma unroll
    for (int uu = 0; uu < 4; uu++) acc2[uu] = b2[lane + 64 * uu];
    for (int k = 0; k < 64; k++){
      float v0 = __shfl(y0, k);
      float v1 = __shfl(y1, k);
      #pragma unroll
      for (int uu = 0; uu < 4; uu++){
        const float* wr = W2 + (lane + 64 * uu) * 128;
        acc2[uu] += v0 * wr[k] + v1 * wr[k + 64];
      }
    }
    #pragma unroll
    for (int uu = 0; uu < 4; uu++) acc2[uu] = gelu(acc2[uu]);
    float s = acc2[0] + acc2[1] + acc2[2] + acc2[3];
    mean = wred(s) * (1.0f / 256.0f);
    float vv = 0.0f;
    #pragma unroll
    for (int uu = 0; uu < 4; uu++){ float d = acc2[uu] - mean; vv += d * d; }
    inv = rsqrtf(wred(vv) * (1.0f / 256.0f) + 1e-5f);
    short* eb = encg + g * 16384;
    const int rt_e = row_l >> 4, rin_e = row_l & 15;
    const int qe = (lane >> 3) & 3, je = lane & 7;
    #pragma unroll
    for (int uu = 0; uu < 4; uu++){
      const int c = lane + 64 * uu;
      const float e = (acc2[uu] - mean) * inv * g2[c] + be2[c];
      stc2(eb + (rt_e * 8 + (c >> 5)) * 512 + (qe * 16 + rin_e) * 8 + je, f2bf(e));
    }
  }
  arrive_bar(cnt0 + 258, tid);
  wait_bar(cnt0 + 258, tid);                   // enc visible group-wide

  // ---- stage enc -> ldsH0; xp = enc @ Wih0_slice + (bih0+bhh0) ----
  {
    const u64* src = (const u64*)(encg + g * 16384);
    u64 t[8];
    #pragma unroll
    for (int u = 0; u < 8; u++) t[u] = ldc8(src + tid + u * 512);
    #pragma unroll
    for (int u = 0; u < 8; u++) ((u64*)ldsH0)[tid + u * 512] = t[u];
  }
  wbar();
  f4v xp[4];
  {
    s8v Wi0[8];
    #pragma unroll
    for (int kk = 0; kk < 8; kk++)
      Wi0[kk] = *(const s8v*)(img + sIdx * 16384 + gate * 4096 + kk * 512 + (lane << 3));
    const float bi = bih0[n0] + bhh0[n0];
    #pragma unroll
    for (int rt = 0; rt < 4; rt++){ f4v t = {bi, bi, bi, bi}; xp[rt] = t; }
    const short* A0 = ldsH0 + (lane << 3);
    #pragma unroll
    for (int rt = 0; rt < 4; rt++)
      #pragma unroll
      for (int kk = 0; kk < 8; kk++)
        xp[rt] = mfma16(*(const s8v*)(A0 + (rt * 8 + kk) * 512), Wi0[kk], xp[rt]);
  }
  wbar();                                      // ldsH0 free for s=0 stage

  float c0[4] = {0.f,0.f,0.f,0.f}, c1[4] = {0.f,0.f,0.f,0.f};

  // ---- prologue: prefetch h0(0) (parity 0; buffer memset-zero) ----
  u64 t0[8];
  {
    const u64* h0src = (const u64*)(h0g + (0 * 32 + g) * 16384);
    #pragma unroll
    for (int u = 0; u < 8; u++) t0[u] = ldc8(h0src + tid + u * 512);
  }

  // ------------------ split-barrier recurrence: iter s in [0,257] ----------
  // critical: h0(s+1)=f(h0(s)) publish + arrive cnt0(s)       [s<=255]
  // shadow:   h1(s)=f(h0(s),h1(s-1)) publish + arrive cnt1(s) [1<=s<=256]
  //           decoder(staged h1(s-1)) -> out col s-2          [s>=2]
  //           + prefetch h0(s+1) into t0 after wait cnt0(s)   [s<=255]
  #pragma unroll 1
  for (int s = 0; s <= 257; s++){
    const bool stg0 = (s <= 256);    // h0(s) in t0 -> LDS (h1(256) needs h0(256))
    const bool g0c  = (s <= 255);    // acc0 + publish h0(s+1)
    const bool gPc  = (s <= 256);    // accP = bs1 + h0@Bi1
    const bool stg1 = (s >= 1);      // stage h1(s-1)
    const bool g1c  = (s >= 1 && s <= 256);  // accP += h1@Bh1, publish h1(s)
    const bool decM = (s >= 2);      // decoder on staged h1(s-1), out col s-2

    // ---- critical: h0(s) regs -> LDS (prefetched at s-1), gemm, publish ----
    if (stg0){
      asm volatile("s_waitcnt vmcnt(0)" ::: "memory");  // t0 loads complete
      #pragma unroll
      for (int u = 0; u < 8; u++) ((u64*)ldsH0)[tid + u * 512] = t0[u];
    }
    wbar();                                           // (1) h0 staged

    f4v acc0[4], accP[4];
    if (stg0){
      #pragma unroll
      for (int rt = 0; rt < 4; rt++){
        acc0[rt] = xp[rt];
        f4v t = {bs1v, bs1v, bs1v, bs1v};
        accP[rt] = t;
      }
      const short* A0 = ldsH0 + (lane << 3);
      if (g0c){
        #pragma unroll
        for (int rt = 0; rt < 4; rt++)
          #pragma unroll
          for (int kk = 0; kk < 8; kk++){
            const s8v a = *(const s8v*)(A0 + (rt * 8 + kk) * 512);
            acc0[rt] = mfma16(a, Bh0[kk], acc0[rt]);
            accP[rt] = mfma16(a, Bi1[kk], accP[rt]);
          }
      } else if (gPc){
        #pragma unroll
        for (int rt = 0; rt < 4; rt++)
          #pragma unroll
          for (int kk = 0; kk < 8; kk++)
            accP[rt] = mfma16(*(const s8v*)(A0 + (rt * 8 + kk) * 512), Bi1[kk], accP[rt]);
      }
    }
    if (g0c){
      #pragma unroll
      for (int rt = 0; rt < 4; rt++)
        #pragma unroll
        for (int r = 0; r < 4; r++)
          Gst[0][(gate * 64 + rt * 16 + q * 4 + r) * 36 + ch * 16 + m16] = acc0[rt][r];
    }
    wbar();                                           // (2) G0 visible
    if (g0c){
      const float* G0 = &Gst[0][0];
      const f4v gi = *(const f4v*)&G0[(0 * 64 + rowp) * 36 + coltp];
      const f4v gf = *(const f4v*)&G0[(1 * 64 + rowp) * 36 + coltp];
      const f4v gg = *(const f4v*)&G0[(2 * 64 + rowp) * 36 + coltp];
      const f4v go = *(const f4v*)&G0[(3 * 64 + rowp) * 36 + coltp];
      u64 pk = 0;
      #pragma unroll
      for (int j = 0; j < 4; j++){
        const float ii = sigm(gi[j]), ff = sigm(gf[j]);
        const float ga = tnh(gg[j]),  oo = sigm(go[j]);
        c0[j] = ff * c0[j] + ii * ga;
        pk |= (u64)(unsigned short)f2bf(oo * tnh(c0[j])) << (16 * j);
      }
      stc8((u64*)(h0g + ((((s + 1) & 1)) * 32 + g) * 16384 + pub_off), pk);
      arrive_bar(cnt0 + s, tid);                      // MID-ITER arrive
    }

    // ---- shadow: wait h1(s-1) (near-instant), stage, finish layer 1 ----
    if (s >= 2 && stg1) wait_bar(cnt1 + (s - 1), tid);  // s=1: h1(0) pre-zeroed
    if (stg1){
      const u64* h1src = (const u64*)(h1g + ((((s + 1) & 1)) * 32 + g) * 16384);
      u64 t1[8];
      #pragma unroll
      for (int u = 0; u < 8; u++) t1[u] = ldc8(h1src + tid + u * 512);
      #pragma unroll
      for (int u = 0; u < 8; u++) ((u64*)ldsX)[tid + u * 512] = t1[u];
    }
    wbar();                                           // (3) h1 staged

    if (g1c){
      const short* A1 = ldsX + (lane << 3);
      #pragma unroll
      for (int rt = 0; rt < 4; rt++)
        #pragma unroll
        for (int kk = 0; kk < 8; kk++)
          accP[rt] = mfma16(*(const s8v*)(A1 + (rt * 8 + kk) * 512), Bh1[kk], accP[rt]);
    }
    f4v ad = {0.f, 0.f, 0.f, 0.f};
    if (decM){
      #pragma unroll
      for (int kk = 0; kk < 8; kk++){
        const s8v a3 = *(const s8v*)(ldsX + (rt3 * 8 + kk) * 512 + (q * 16 + rin3) * 8);
        ad = mfma16(a3, W3r[kk], ad);
      }
    }

    // ---- prefetch h0(s+1): wait cnt0(s) (peers arrived mid-critical),
    //      issue loads into t0; they complete under G1/pointwise/publish ----
    if (g0c){
      wait_bar(cnt0 + s, tid);
      const u64* h0srcN = (const u64*)(h0g + ((((s + 1) & 1)) * 32 + g) * 16384);
      #pragma unroll
      for (int u = 0; u < 8; u++) t0[u] = ldc8(h0srcN + tid + u * 512);
    }

    if (g1c){
      #pragma unroll
      for (int rt = 0; rt < 4; rt++)
        #pragma unroll
        for (int r = 0; r < 4; r++)
          Gst[1][(gate * 64 + rt * 16 + q * 4 + r) * 36 + ch * 16 + m16] = accP[rt][r];
    }
    wbar();                                           // (4) G1 visible

    if (g1c){
      const float* G1 = &Gst[1][0];
      const f4v gi = *(const f4v*)&G1[(0 * 64 + rowp) * 36 + coltp];
      const f4v gf = *(const f4v*)&G1[(1 * 64 + rowp) * 36 + coltp];
      const f4v gg = *(const f4v*)&G1[(2 * 64 + rowp) * 36 + coltp];
      const f4v go = *(const f4v*)&G1[(3 * 64 + rowp) * 36 + coltp];
      u64 pk = 0;
      #pragma unroll
      for (int j = 0; j < 4; j++){
        const float ii = sigm(gi[j]), ff = sigm(gf[j]);
        const float ga = tnh(gg[j]),  oo = sigm(go[j]);
        c1[j] = ff * c1[j] + ii * ga;
        pk |= (u64)(unsigned short)f2bf(oo * tnh(c1[j])) << (16 * j);
      }
      stc8((u64*)(h1g + ((s & 1) * 32 + g) * 16384 + pub_off), pk);
    }
    if (decM){
      float p0[4], p1[4];
      #pragma unroll
      for (int r = 0; r < 4; r++){
        const float dv = gelu(ad[r] + b3c);
        p0[r] = dv * w40;
        p1[r] = dv * w41;
      }
      #pragma unroll
      for (int mk = 1; mk < 16; mk <<= 1)
        #pragma unroll
        for (int r = 0; r < 4; r++){
          p0[r] += __shfl_xor(p0[r], mk);
          p1[r] += __shfl_xor(p1[r], mk);
        }
      if (m16 == 0 && q < 2){
        #pragma unroll
        for (int r = 0; r < 4; r++){
          pstg[(v * 8 + q * 4 + r) * 2 + 0] = p0[r];
          pstg[(v * 8 + q * 4 + r) * 2 + 1] = p1[r];
        }
      }
    }
    if (g1c) arrive_bar(cnt1 + s, tid);               // END-ITER arrive
    else     wbar();                                  // pstg visibility (s=0,257)
    if (decM && tid < 16){
      const int row = tid >> 1, o = tid & 1;
      float sum = b4o;
      #pragma unroll
      for (int w2 = 0; w2 < 8; w2++) sum += pstg[(w2 * 8 + row) * 2 + o];
      out[((size_t)(g * 64 + m * 8 + row) * 256 + (s - 2)) * 2 + o] = sum;
    }
  }
}

extern "C" void kernel_launch(void* const* d_in, const int* in_sizes, int n_in,
                              void* d_out, int out_size, void* d_ws, size_t ws_size,
                              hipStream_t stream)
{
  const float* x    = (const float*)d_in[0];
  const float* W1   = (const float*)d_in[1];
  const float* b1   = (const float*)d_in[2];
  const float* g1   = (const float*)d_in[3];
  const float* be1  = (const float*)d_in[4];
  const float* W2   = (const float*)d_in[5];
  const float* b2   = (const float*)d_in[6];
  const float* g2   = (const float*)d_in[7];
  const float* be2  = (const float*)d_in[8];
  const float* Wih0 = (const float*)d_in[9];
  const float* Whh0 = (const float*)d_in[10];
  const float* bih0 = (const float*)d_in[11];
  const float* bhh0 = (const float*)d_in[12];
  const float* Wih1 = (const float*)d_in[13];
  const float* Whh1 = (const float*)d_in[14];
  const float* bih1 = (const float*)d_in[15];
  const float* bhh1 = (const float*)d_in[16];
  const float* W3   = (const float*)d_in[17];
  const float* b3   = (const float*)d_in[18];
  const float* W4   = (const float*)d_in[19];
  const float* b4   = (const float*)d_in[20];

  short* wsb = (short*)d_ws;

  prep_kernel<<<4232, 256, 0, stream>>>(Wih0, Whh0, Wih1, Whh1, W3, W4, wsb);
  // zero h0g + h1g + counters: bytes [2*H0G_SH, +2*(1048576*2 + 33280))
  hipMemsetAsync((char*)d_ws + 2168832, 0, 4260864, stream);
  curve_rec<<<256, 512, 0, stream>>>(x, W1, b1, g1, be1, W2, b2, g2, be2,
                                     bih0, bhh0, bih1, bhh1, b3, b4, W4, wsb,
                                     (float*)d_out);
}